// Round 3
// 725.097 us; speedup vs baseline: 1.0557x; 1.0557x over previous
//
#include <hip/hip_runtime.h>

// gen_En: En[r,c] = sum_{i,j,m} w[i*32+j,m] * Ey[(i*32+j)*4+m, r-32i, c-32j]
// with w = (neff*N0/(neff+N0)) * U, valid when 0 <= r-32i < 192, 0 <= c-32j < 192.
// Each Ey element contributes to exactly ONE En element -> pure streaming,
// no atomics, no init. Per 32x32 output tile (ti,tj), contributing (i,j) are
// i = ti-di, j = tj-dj for di,dj in [0,6) intersected with [0,32).
//
// Interior tiles (full 6x6 window set) take a fully-unrolled compile-time
// path (deep load pipelining); 32-bit element offsets off a single base
// (saddr + voffset codegen); nontemporal loads/stores (zero reuse).

#define NB 32           // N blocks per dim
#define MODES 4
#define OUT_RES 32
#define EYS 192         // EY_SIZE
#define TOTAL 1184
#define N0F 1.5f
#define PLANE (EYS * EYS)          // 36864 floats per (k,m) plane
#define KSTRIDE (MODES * PLANE)    // 147456 floats per k

// Native clang vector type — valid operand for __builtin_nontemporal_*.
typedef float floatx4 __attribute__((ext_vector_type(4)));

__global__ __launch_bounds__(256) void en_gather_kernel(
    const float* __restrict__ U,
    const float* __restrict__ neff,
    const float* __restrict__ Ey,
    float* __restrict__ En)
{
    const int tj = blockIdx.x;   // output column tile index, 0..36
    const int ti = blockIdx.y;   // output row tile index, 0..36
    const int t  = threadIdx.x;

    // Weights staged as [di][dj][m], zero-padded where (i,j) out of range.
    __shared__ float wsh[6 * 6 * MODES];
    if (t < 6 * 6 * MODES) {
        const int m  = t & 3;
        const int p  = t >> 2;    // di*6 + dj
        const int dj = p % 6;
        const int di = p / 6;
        const int i = ti - di;
        const int j = tj - dj;
        float w = 0.f;
        if ((unsigned)i < NB && (unsigned)j < NB) {
            const int k = i * NB + j;
            const float e = neff[k * MODES + m];
            w = e * N0F / (e + N0F) * U[k * MODES + m];
        }
        wsh[t] = w;
    }
    __syncthreads();

    // Thread -> (row, 4 cols) within the 32x32 tile
    const int r_local = t >> 3;          // 0..31
    const int c_local = (t & 7) << 2;    // 0,4,...,28
    const unsigned thr_off = (unsigned)(r_local * EYS + c_local);

    floatx4 acc = {0.f, 0.f, 0.f, 0.f};

    const bool interior = (ti >= 5) && (ti <= 31) && (tj >= 5) && (tj <= 31);

    if (interior) {
        // All 36 windows valid: fully unrolled, compile-time bounds.
#pragma unroll
        for (int di = 0; di < 6; ++di) {
            const int i = ti - di;
#pragma unroll
            for (int dj = 0; dj < 6; ++dj) {
                const int j = tj - dj;
                const unsigned uni =
                    (unsigned)((i * NB + j) * KSTRIDE
                               + di * (OUT_RES * EYS) + dj * OUT_RES);
                const float* wp = &wsh[(di * 6 + dj) * MODES];
                const float* base = Ey + uni + thr_off;
#pragma unroll
                for (int m = 0; m < MODES; ++m) {
                    const floatx4 v = __builtin_nontemporal_load(
                        reinterpret_cast<const floatx4*>(base + m * PLANE));
                    acc += wp[m] * v;
                }
            }
        }
    } else {
        // Edge tiles: runtime-guarded, same body.
        for (int di = 0; di < 6; ++di) {
            const int i = ti - di;
            if ((unsigned)i >= NB) continue;
            for (int dj = 0; dj < 6; ++dj) {
                const int j = tj - dj;
                if ((unsigned)j >= NB) continue;
                const unsigned uni =
                    (unsigned)((i * NB + j) * KSTRIDE
                               + di * (OUT_RES * EYS) + dj * OUT_RES);
                const float* wp = &wsh[(di * 6 + dj) * MODES];
                const float* base = Ey + uni + thr_off;
#pragma unroll
                for (int m = 0; m < MODES; ++m) {
                    const floatx4 v = __builtin_nontemporal_load(
                        reinterpret_cast<const floatx4*>(base + m * PLANE));
                    acc += wp[m] * v;
                }
            }
        }
    }

    floatx4* outp = reinterpret_cast<floatx4*>(
        En + (size_t)(ti * OUT_RES + r_local) * TOTAL
           + (tj * OUT_RES + c_local));
    __builtin_nontemporal_store(acc, outp);
}

extern "C" void kernel_launch(void* const* d_in, const int* in_sizes, int n_in,
                              void* d_out, int out_size, void* d_ws, size_t ws_size,
                              hipStream_t stream) {
    // inputs: hs (unused), U, neff, Ey — all fp32
    const float* U    = (const float*)d_in[1];
    const float* neff = (const float*)d_in[2];
    const float* Ey   = (const float*)d_in[3];
    float* En = (float*)d_out;

    dim3 grid(TOTAL / OUT_RES, TOTAL / OUT_RES);  // 37 x 37
    en_gather_kernel<<<grid, 256, 0, stream>>>(U, neff, Ey, En);
}